// Round 6
// baseline (367.870 us; speedup 1.0000x reference)
//
#include <hip/hip_runtime.h>

#define DT     0.0005f
#define NENV   1024
#define NB     25
#define SPF    10
#define NFRM   16
#define NF01   15                     // frames 1..15
#define TQ_SLAB (NENV*31)
#define RF_SLAB (NENV*156)
#define SNAP_STRIDE 64
#define SNAP_FLOATS (NFRM*NENV*SNAP_STRIDE)   // 1048576 floats = 4.19 MB
#define NJ      (NENV*NB)             // 25600
#define K1_JBLOCKS (NJ*NF01/256)      // 1500
#define K1_RBLOCKS (NENV/256)         // 4
#define WS_NEED_BYTES ((size_t)(SNAP_FLOATS + NJ*NF01*2)*4)

// ===========================================================================
// K1: frame-parallel joint pass + sequential root pass (block-role split).
// Joint: thread per (env, joint, frame). The joint ODE is affine:
//   jqd' = a10*jq + a11*jqd + dti*u,  jq' = jq + DT*jqd'
// with u = tau + ke*ref + rf.axis (input-only). Running the recurrence from
// (0,0) over the frame's 10 steps yields the frame's affine offset c_f.
// ===========================================================================
__global__ void k1_kernel(
    const float* __restrict__ q_init,
    const float* __restrict__ qd_init,
    const float* __restrict__ torques,
    const float* __restrict__ res_f,
    const float* __restrict__ refs,
    const float* __restrict__ target_ke,
    const float* __restrict__ target_kd,
    const float* __restrict__ body_mass,
    const float* __restrict__ joint_axes,
    float* __restrict__ snap,          // (16,1024,64)
    float2* __restrict__ cws)          // (15, 25600)
{
    const int bid = (int)blockIdx.x;
    if (bid < K1_JBLOCKS) {
        const int g   = bid*256 + (int)threadIdx.x;      // 0..383999
        const int f01 = g / NJ;                          // 0..14
        const int r   = g - f01*NJ;                      // 0..25599
        const int env = r / NB;
        const int j   = r - env*NB;

        float a0 = joint_axes[j*3+0];
        float a1 = joint_axes[j*3+1];
        float a2 = joint_axes[j*3+2];
        float rn = 1.0f / fmaxf(sqrtf(a0*a0 + a1*a1 + a2*a2), 1e-8f);
        const float ax = a0*rn, ay = a1*rn, az = a2*rn;
        const float ke   = target_ke[env*NB + j];
        const float kd   = target_kd[env*NB + j];
        const float invm = 1.0f / (body_mass[env*(NB+1) + 1 + j] + 0.1f);
        const float dti  = DT*invm;
        const float a11  = 1.0f - DT*kd*invm;
        const float a10  = -DT*ke*invm;

        const int tq_off = env*31  + 6 + j;
        const int rf_off = env*156 + 6 + 6*j;

        float  ta[SPF], rr[SPF], r2[SPF];
        float2 ab[SPF];
        #pragma unroll
        for (int k = 0; k < SPF; ++k) {
            const int s = f01*SPF + k;
            ta[k] = torques[(size_t)s*TQ_SLAB + tq_off];
            rr[k] = refs   [(size_t)s*TQ_SLAB + tq_off];
            const float* rf = res_f + (size_t)s*RF_SLAB + rf_off;
            ab[k] = *(const float2*)rf;
            r2[k] = rf[2];
        }
        float cq = 0.0f, cd = 0.0f;
        #pragma unroll
        for (int k = 0; k < SPF; ++k) {
            float u = ta[k] + ke*rr[k] + (ab[k].x*ax + ab[k].y*ay + r2[k]*az);
            cd = a10*cq + a11*cd + dti*u;
            cq += DT*cd;
        }
        cws[(size_t)f01*NJ + r] = make_float2(cq, cd);
    } else {
        // -------- root path: sequential 150 steps, batched loads/frame ------
        const int env = (bid - K1_JBLOCKS)*256 + (int)threadIdx.x;  // 0..1023

        float px = q_init[env*32+0], py = q_init[env*32+1], pz = q_init[env*32+2];
        float q0 = q_init[env*32+3], q1 = q_init[env*32+4];
        float q2 = q_init[env*32+5], q3 = q_init[env*32+6];
        float rn = 1.0f / fmaxf(sqrtf(q0*q0 + q1*q1 + q2*q2 + q3*q3), 1e-8f);
        float qx = q0*rn, qy = q1*rn, qz = q2*rn, qw = q3*rn;
        float wx = qd_init[env*31+0], wy = qd_init[env*31+1], wz = qd_init[env*31+2];
        float vx = qd_init[env*31+3], vy = qd_init[env*31+4], vz = qd_init[env*31+5];
        const float invm0 = 1.0f / (body_mass[env*(NB+1)] + 0.1f);

        {
            float* sp = snap + (size_t)env * SNAP_STRIDE;
            sp[0]=px; sp[1]=py; sp[2]=pz;
            sp[3]=qx; sp[4]=qy; sp[5]=qz; sp[6]=qw;
            sp[7]=wx; sp[8]=wy; sp[9]=wz;
            sp[10]=vx; sp[11]=vy; sp[12]=vz;
        }

        #pragma unroll 1
        for (int f = 1; f < NFRM; ++f) {
            float  tb[SPF][6];
            float4 ra[SPF];   // rf[0..3]
            float2 rb[SPF];   // rf[4..5]
            #pragma unroll
            for (int k = 0; k < SPF; ++k) {
                const int s = (f-1)*SPF + k;
                const float* tq = torques + (size_t)s*TQ_SLAB + env*31;
                tb[k][0]=tq[0]; tb[k][1]=tq[1]; tb[k][2]=tq[2];
                tb[k][3]=tq[3]; tb[k][4]=tq[4]; tb[k][5]=tq[5];
                const float* rf = res_f + (size_t)s*RF_SLAB + env*156;
                ra[k] = *(const float4*)rf;
                rb[k] = *(const float2*)(rf + 4);
            }
            #pragma unroll
            for (int k = 0; k < SPF; ++k) {
                vx += DT * ((tb[k][3] + ra[k].w) * invm0);
                vy += DT * ((tb[k][4] + rb[k].x) * invm0);
                vz += DT * ((tb[k][5] + rb[k].y) * invm0 - 9.81f);
                wx += DT * (tb[k][0] + ra[k].x) * invm0;
                wy += DT * (tb[k][1] + ra[k].y) * invm0;
                wz += DT * (tb[k][2] + ra[k].z) * invm0;
                px += DT * vx; py += DT * vy; pz += DT * vz;
                float dqx =  wx*qw + wy*qz - wz*qy;
                float dqy = -wx*qz + wy*qw + wz*qx;
                float dqz =  wx*qy - wy*qx + wz*qw;
                float dqw = -(wx*qx + wy*qy + wz*qz);
                float nqx = qx + 0.5f*DT*dqx;
                float nqy = qy + 0.5f*DT*dqy;
                float nqz = qz + 0.5f*DT*dqz;
                float nqw = qw + 0.5f*DT*dqw;
                float nrm = sqrtf(nqx*nqx + nqy*nqy + nqz*nqz + nqw*nqw);
                float rq  = 1.0f / fmaxf(nrm, 1e-8f);
                qx = nqx*rq; qy = nqy*rq; qz = nqz*rq; qw = nqw*rq;
            }
            float* sp = snap + ((size_t)f*NENV + env) * SNAP_STRIDE;
            sp[0]=px; sp[1]=py; sp[2]=pz;
            sp[3]=qx; sp[4]=qy; sp[5]=qz; sp[6]=qw;
            sp[7]=wx; sp[8]=wy; sp[9]=wz;
            sp[10]=vx; sp[11]=vy; sp[12]=vz;
        }
    }
}

// ===========================================================================
// K2: per (env,joint) compose 15 frames: x <- M x + c_f, M = A^10 (rebuilt
// locally by running the homogeneous recurrence on unit vectors).
// ===========================================================================
__global__ void k2_kernel(
    const float* __restrict__ q_init,
    const float* __restrict__ qd_init,
    const float* __restrict__ target_ke,
    const float* __restrict__ target_kd,
    const float* __restrict__ body_mass,
    const float2* __restrict__ cws,    // (15, 25600)
    float* __restrict__ snap)
{
    const int r   = (int)(blockIdx.x*256 + threadIdx.x);   // 0..25599
    const int env = r / NB;
    const int j   = r - env*NB;

    const float ke   = target_ke[env*NB + j];
    const float kd   = target_kd[env*NB + j];
    const float invm = 1.0f / (body_mass[env*(NB+1) + 1 + j] + 0.1f);
    const float a11  = 1.0f - DT*kd*invm;
    const float a10  = -DT*ke*invm;

    // M = A^10 via two unit-vector runs of the homogeneous recurrence
    float m00 = 1.0f, m10 = 0.0f, m01 = 0.0f, m11 = 1.0f;
    #pragma unroll
    for (int k = 0; k < SPF; ++k) {
        m10 = a10*m00 + a11*m10;  m00 += DT*m10;
        m11 = a10*m01 + a11*m11;  m01 += DT*m11;
    }

    float jq  = q_init [env*32 + 7 + j];
    float jqd = qd_init[env*31 + 6 + j];

    snap[(size_t)env*SNAP_STRIDE + 13 + j] = jq;
    snap[(size_t)env*SNAP_STRIDE + 38 + j] = jqd;

    float2 c[NF01];
    #pragma unroll
    for (int f = 0; f < NF01; ++f) c[f] = cws[(size_t)f*NJ + r];

    #pragma unroll
    for (int f = 0; f < NF01; ++f) {
        float nq = m00*jq + m01*jqd + c[f].x;
        float nd = m10*jq + m11*jqd + c[f].y;
        jq = nq; jqd = nd;
        float* sp = snap + ((size_t)(f+1)*NENV + env) * SNAP_STRIDE;
        sp[13 + j] = jq;
        sp[38 + j] = jqd;
    }
}

// ===========================================================================
// K3: FK. One thread per (frame, env); chain run twice (pos pass / vel pass);
// rows staged in LDS, flushed with coalesced float4 stores.
// ===========================================================================
template<int PASS>
__device__ __forceinline__ void fk_chain(
    const float st[64],
    const float* __restrict__ joint_axes,
    const float* __restrict__ joint_offsets,
    float* __restrict__ lds, int tid)
{
    float px=st[0], py=st[1], pz=st[2];
    float qx=st[3], qy=st[4], qz=st[5], qw=st[6];
    float wx=st[7], wy=st[8], wz=st[9];
    float vx=st[10], vy=st[11], vz=st[12];

    if (PASS == 0) {
        float* p = lds + tid*182;
        p[0]=px; p[1]=py; p[2]=pz; p[3]=qx; p[4]=qy; p[5]=qz; p[6]=qw;
    } else {
        float* p = lds + tid*156;
        p[0]=wx; p[1]=wy; p[2]=wz; p[3]=vx; p[4]=vy; p[5]=vz;
    }

    #pragma unroll
    for (int b = 0; b < NB; ++b) {
        float a0=joint_axes[b*3+0], a1=joint_axes[b*3+1], a2=joint_axes[b*3+2];
        float rn = 1.0f / fmaxf(sqrtf(a0*a0 + a1*a1 + a2*a2), 1e-8f);
        float axn=a0*rn, ayn=a1*rn, azn=a2*rn;
        float ox=joint_offsets[b*3+0], oy=joint_offsets[b*3+1], oz=joint_offsets[b*3+2];

        float tx = 2.0f*(qy*oz - qz*oy);
        float ty = 2.0f*(qz*ox - qx*oz);
        float tz = 2.0f*(qx*oy - qy*ox);
        float owx = ox + qw*tx + (qy*tz - qz*ty);
        float owy = oy + qw*ty + (qz*tx - qx*tz);
        float owz = oz + qw*tz + (qx*ty - qy*tx);

        float pcx = px + owx, pcy = py + owy, pcz = pz + owz;

        float half = 0.5f * st[13+b];
        float sh, ch;
        __sincosf(half, &sh, &ch);
        float bx = axn*sh, by = ayn*sh, bz = azn*sh, bw = ch;
        float qcx = qw*bx + qx*bw + qy*bz - qz*by;
        float qcy = qw*by - qx*bz + qy*bw + qz*bx;
        float qcz = qw*bz + qx*by - qy*bx + qz*bw;
        float qcw = qw*bw - qx*bx - qy*by - qz*bz;

        float ux = 2.0f*(qy*azn - qz*ayn);
        float uy = 2.0f*(qz*axn - qx*azn);
        float uz = 2.0f*(qx*ayn - qy*axn);
        float awx = axn + qw*ux + (qy*uz - qz*uy);
        float awy = ayn + qw*uy + (qz*ux - qx*uz);
        float awz = azn + qw*uz + (qx*uy - qy*ux);

        float thd = st[38+b];
        float wcx = wx + awx*thd, wcy = wy + awy*thd, wcz = wz + awz*thd;
        float vcx = vx + (wy*owz - wz*owy);
        float vcy = vy + (wz*owx - wx*owz);
        float vcz = vz + (wx*owy - wy*owx);

        px=pcx; py=pcy; pz=pcz;
        qx=qcx; qy=qcy; qz=qcz; qw=qcw;
        wx=wcx; wy=wcy; wz=wcz;
        vx=vcx; vy=vcy; vz=vcz;

        if (PASS == 0) {
            float* p = lds + tid*182 + (b+1)*7;
            p[0]=px; p[1]=py; p[2]=pz; p[3]=qx; p[4]=qy; p[5]=qz; p[6]=qw;
        } else {
            float* p = lds + tid*156 + (b+1)*6;
            p[0]=wx; p[1]=wy; p[2]=wz; p[3]=vx; p[4]=vy; p[5]=vz;
        }
    }
}

__global__ __launch_bounds__(64) void fk_kernel(
    const float* __restrict__ snap,
    const float* __restrict__ joint_axes,
    const float* __restrict__ joint_offsets,
    float* __restrict__ out)
{
    __shared__ float lds[64*182];          // 46592 B
    const int tid = (int)threadIdx.x;
    const int t   = (int)blockIdx.x*64 + tid;
    const int f   = t >> 10;
    const int e0  = (int)((blockIdx.x*64) & 1023);

    float st[64];
    {
        const float4* sp4 = (const float4*)(snap + (size_t)t * SNAP_STRIDE);
        #pragma unroll
        for (int i = 0; i < 16; ++i) ((float4*)st)[i] = sp4[i];
    }

    fk_chain<0>(st, joint_axes, joint_offsets, lds, tid);
    __syncthreads();
    {
        float4* o4 = (float4*)(out + (size_t)(f*NENV + e0)*182);
        const float4* l4 = (const float4*)lds;
        for (int i = tid; i < 64*182/4; i += 64) o4[i] = l4[i];
    }
    __syncthreads();
    fk_chain<1>(st, joint_axes, joint_offsets, lds, tid);
    __syncthreads();
    {
        float4* o4 = (float4*)(out + (size_t)NFRM*NENV*182 + (size_t)(f*NENV + e0)*156);
        const float4* l4 = (const float4*)lds;
        for (int i = tid; i < 64*156/4; i += 64) o4[i] = l4[i];
    }
}

// ===========================================================================
// Fallback integrate (round-4 proven path) if ws is too small for cws.
// ===========================================================================
__global__ __launch_bounds__(64) void integrate_fallback(
    const float* __restrict__ q_init,
    const float* __restrict__ qd_init,
    const float* __restrict__ torques,
    const float* __restrict__ res_f,
    const float* __restrict__ refs,
    const float* __restrict__ target_ke,
    const float* __restrict__ target_kd,
    const float* __restrict__ body_mass,
    const float* __restrict__ joint_axes,
    float* __restrict__ snap)
{
    const int bid = (int)blockIdx.x;
    if (bid < NJ/64) {
        const int t   = bid*64 + (int)threadIdx.x;
        const int env = t / NB;
        const int j   = t - env*NB;
        float a0 = joint_axes[j*3+0], a1 = joint_axes[j*3+1], a2 = joint_axes[j*3+2];
        float rn = 1.0f / fmaxf(sqrtf(a0*a0 + a1*a1 + a2*a2), 1e-8f);
        const float ax = a0*rn, ay = a1*rn, az = a2*rn;
        const float ke   = target_ke[env*NB + j];
        const float kd   = target_kd[env*NB + j];
        const float invm = 1.0f / (body_mass[env*(NB+1) + 1 + j] + 0.1f);
        float jq  = q_init [env*32 + 7 + j];
        float jqd = qd_init[env*31 + 6 + j];
        const int tq_off = env*31  + 6 + j;
        const int rf_off = env*156 + 6 + 6*j;
        snap[(size_t)env*SNAP_STRIDE + 13 + j] = jq;
        snap[(size_t)env*SNAP_STRIDE + 38 + j] = jqd;
        #pragma unroll 1
        for (int f = 1; f < NFRM; ++f) {
            float ta[SPF], rr[SPF], r0[SPF], r1[SPF], r2[SPF];
            #pragma unroll
            for (int k = 0; k < SPF; ++k) {
                const int s = (f-1)*SPF + k;
                ta[k] = torques[(size_t)s*TQ_SLAB + tq_off];
                rr[k] = refs   [(size_t)s*TQ_SLAB + tq_off];
                const float* rf = res_f + (size_t)s*RF_SLAB + rf_off;
                float2 ab = *(const float2*)rf;
                r0[k] = ab.x; r1[k] = ab.y; r2[k] = rf[2];
            }
            #pragma unroll
            for (int k = 0; k < SPF; ++k) {
                float rftau = r0[k]*ax + r1[k]*ay + r2[k]*az;
                float tj = ta[k] + ke*(rr[k] - jq) - kd*jqd + rftau;
                jqd += DT * tj * invm;
                jq  += DT * jqd;
            }
            float* sp = snap + ((size_t)f*NENV + env) * SNAP_STRIDE;
            sp[13 + j] = jq; sp[38 + j] = jqd;
        }
    } else {
        const int env = (bid - NJ/64)*64 + (int)threadIdx.x;
        float px = q_init[env*32+0], py = q_init[env*32+1], pz = q_init[env*32+2];
        float q0 = q_init[env*32+3], q1 = q_init[env*32+4];
        float q2 = q_init[env*32+5], q3 = q_init[env*32+6];
        float rn = 1.0f / fmaxf(sqrtf(q0*q0 + q1*q1 + q2*q2 + q3*q3), 1e-8f);
        float qx = q0*rn, qy = q1*rn, qz = q2*rn, qw = q3*rn;
        float wx = qd_init[env*31+0], wy = qd_init[env*31+1], wz = qd_init[env*31+2];
        float vx = qd_init[env*31+3], vy = qd_init[env*31+4], vz = qd_init[env*31+5];
        const float invm0 = 1.0f / (body_mass[env*(NB+1)] + 0.1f);
        {
            float* sp = snap + (size_t)env * SNAP_STRIDE;
            sp[0]=px; sp[1]=py; sp[2]=pz; sp[3]=qx; sp[4]=qy; sp[5]=qz; sp[6]=qw;
            sp[7]=wx; sp[8]=wy; sp[9]=wz; sp[10]=vx; sp[11]=vy; sp[12]=vz;
        }
        #pragma unroll 1
        for (int f = 1; f < NFRM; ++f) {
            float  tb[SPF][6]; float4 ra[SPF]; float2 rb[SPF];
            #pragma unroll
            for (int k = 0; k < SPF; ++k) {
                const int s = (f-1)*SPF + k;
                const float* tq = torques + (size_t)s*TQ_SLAB + env*31;
                tb[k][0]=tq[0]; tb[k][1]=tq[1]; tb[k][2]=tq[2];
                tb[k][3]=tq[3]; tb[k][4]=tq[4]; tb[k][5]=tq[5];
                const float* rf = res_f + (size_t)s*RF_SLAB + env*156;
                ra[k] = *(const float4*)rf; rb[k] = *(const float2*)(rf + 4);
            }
            #pragma unroll
            for (int k = 0; k < SPF; ++k) {
                vx += DT * ((tb[k][3] + ra[k].w) * invm0);
                vy += DT * ((tb[k][4] + rb[k].x) * invm0);
                vz += DT * ((tb[k][5] + rb[k].y) * invm0 - 9.81f);
                wx += DT * (tb[k][0] + ra[k].x) * invm0;
                wy += DT * (tb[k][1] + ra[k].y) * invm0;
                wz += DT * (tb[k][2] + ra[k].z) * invm0;
                px += DT * vx; py += DT * vy; pz += DT * vz;
                float dqx =  wx*qw + wy*qz - wz*qy;
                float dqy = -wx*qz + wy*qw + wz*qx;
                float dqz =  wx*qy - wy*qx + wz*qw;
                float dqw = -(wx*qx + wy*qy + wz*qz);
                float nqx = qx + 0.5f*DT*dqx, nqy = qy + 0.5f*DT*dqy;
                float nqz = qz + 0.5f*DT*dqz, nqw = qw + 0.5f*DT*dqw;
                float nrm = sqrtf(nqx*nqx + nqy*nqy + nqz*nqz + nqw*nqw);
                float rq  = 1.0f / fmaxf(nrm, 1e-8f);
                qx = nqx*rq; qy = nqy*rq; qz = nqz*rq; qw = nqw*rq;
            }
            float* sp = snap + ((size_t)f*NENV + env) * SNAP_STRIDE;
            sp[0]=px; sp[1]=py; sp[2]=pz; sp[3]=qx; sp[4]=qy; sp[5]=qz; sp[6]=qw;
            sp[7]=wx; sp[8]=wy; sp[9]=wz; sp[10]=vx; sp[11]=vy; sp[12]=vz;
        }
    }
}

extern "C" void kernel_launch(void* const* d_in, const int* in_sizes, int n_in,
                              void* d_out, int out_size, void* d_ws, size_t ws_size,
                              hipStream_t stream)
{
    const float* q_init     = (const float*)d_in[0];
    const float* qd_init    = (const float*)d_in[1];
    const float* torques    = (const float*)d_in[2];
    const float* res_f      = (const float*)d_in[3];
    const float* refs       = (const float*)d_in[4];
    const float* target_ke  = (const float*)d_in[5];
    const float* target_kd  = (const float*)d_in[6];
    const float* body_mass  = (const float*)d_in[7];
    const float* joint_axes = (const float*)d_in[8];
    const float* joint_offs = (const float*)d_in[9];
    float*  out  = (float*)d_out;
    float*  snap = (float*)d_ws;
    float2* cws  = (float2*)((float*)d_ws + SNAP_FLOATS);

    if (ws_size >= WS_NEED_BYTES) {
        k1_kernel<<<dim3(K1_JBLOCKS + K1_RBLOCKS), dim3(256), 0, stream>>>(
            q_init, qd_init, torques, res_f, refs,
            target_ke, target_kd, body_mass, joint_axes, snap, cws);
        k2_kernel<<<dim3(NJ/256), dim3(256), 0, stream>>>(
            q_init, qd_init, target_ke, target_kd, body_mass, cws, snap);
    } else {
        integrate_fallback<<<dim3(NJ/64 + NENV/64), dim3(64), 0, stream>>>(
            q_init, qd_init, torques, res_f, refs,
            target_ke, target_kd, body_mass, joint_axes, snap);
    }

    fk_kernel<<<dim3(NFRM*NENV/64), dim3(64), 0, stream>>>(
        snap, joint_axes, joint_offs, out);
}

// Round 7
// 252.008 us; speedup vs baseline: 1.4598x; 1.4598x over previous
//
#include <hip/hip_runtime.h>

#define DT     0.0005f
#define NENV   1024
#define NB     25
#define SPF    10
#define NSTEP  150
#define NFRM   16
#define NF01   15
#define TQ_SLAB (NENV*31)
#define RF_SLAB (NENV*156)
#define SNAP_STRIDE 64
#define SNAP_FLOATS (NFRM*NENV*SNAP_STRIDE)      // 1,048,576
#define NJ      (NENV*NB)                        // 25600
#define CWS_FLOATS (NJ*NF01*2)                   // 768,000
#define RT_FLOATS  (NSTEP*NENV*8)                // 1,228,800
#define K1_JBLOCKS (NJ*NF01/256)                 // 1500
#define KA_RDBLOCKS (NSTEP*NENV/256)             // 600
#define K2_BLOCKS  (NJ/256)                      // 100
#define RC_BLOCKS  (NENV/256)                    // 4
#define WS_NEED_NEW    ((size_t)(SNAP_FLOATS + CWS_FLOATS + RT_FLOATS)*4)
#define WS_NEED_LEGACY ((size_t)(SNAP_FLOATS + CWS_FLOATS)*4)

// ===========================================================================
// KA: joint per-frame affine offsets (proven round-6 path)  [bid < 1500]
//   + root per-(step,env) deltas into transposed rt buffer  [bid >= 1500]
// ===========================================================================
__global__ __launch_bounds__(256) void ka_kernel(
    const float* __restrict__ torques,
    const float* __restrict__ res_f,
    const float* __restrict__ refs,
    const float* __restrict__ target_ke,
    const float* __restrict__ target_kd,
    const float* __restrict__ body_mass,
    const float* __restrict__ joint_axes,
    float2* __restrict__ cws,          // (15, 25600)
    float*  __restrict__ rt)           // (150, 1024, 8)
{
    const int bid = (int)blockIdx.x;
    if (bid < K1_JBLOCKS) {
        const int g   = bid*256 + (int)threadIdx.x;
        const int f01 = g / NJ;
        const int r   = g - f01*NJ;
        const int env = r / NB;
        const int j   = r - env*NB;

        float a0 = joint_axes[j*3+0];
        float a1 = joint_axes[j*3+1];
        float a2 = joint_axes[j*3+2];
        float rn = 1.0f / fmaxf(sqrtf(a0*a0 + a1*a1 + a2*a2), 1e-8f);
        const float ax = a0*rn, ay = a1*rn, az = a2*rn;
        const float ke   = target_ke[env*NB + j];
        const float kd   = target_kd[env*NB + j];
        const float invm = 1.0f / (body_mass[env*(NB+1) + 1 + j] + 0.1f);
        const float dti  = DT*invm;
        const float a11  = 1.0f - DT*kd*invm;
        const float a10  = -DT*ke*invm;

        const int tq_off = env*31  + 6 + j;
        const int rf_off = env*156 + 6 + 6*j;

        float  ta[SPF], rr[SPF], r2[SPF];
        float2 ab[SPF];
        #pragma unroll
        for (int k = 0; k < SPF; ++k) {
            const int s = f01*SPF + k;
            ta[k] = torques[(size_t)s*TQ_SLAB + tq_off];
            rr[k] = refs   [(size_t)s*TQ_SLAB + tq_off];
            const float* rf = res_f + (size_t)s*RF_SLAB + rf_off;
            ab[k] = *(const float2*)rf;
            r2[k] = rf[2];
        }
        float cq = 0.0f, cd = 0.0f;
        #pragma unroll
        for (int k = 0; k < SPF; ++k) {
            float u = ta[k] + ke*rr[k] + (ab[k].x*ax + ab[k].y*ay + r2[k]*az);
            cd = a10*cq + a11*cd + dti*u;
            cq += DT*cd;
        }
        cws[(size_t)f01*NJ + r] = make_float2(cq, cd);
    } else {
        // root deltas: thread per (step, env)
        const int g = (bid - K1_JBLOCKS)*256 + (int)threadIdx.x;  // 0..153599
        const int s = g >> 10;
        const int e = g & (NENV-1);
        const float invm0 = 1.0f / (body_mass[e*(NB+1)] + 0.1f);
        const float* tq = torques + (size_t)s*TQ_SLAB + e*31;
        const float t0=tq[0], t1=tq[1], t2=tq[2], t3=tq[3], t4=tq[4], t5=tq[5];
        const float* rf = res_f + (size_t)s*RF_SLAB + e*156;
        const float4 ra = *(const float4*)rf;       // rf[0..3]
        const float2 rb = *(const float2*)(rf + 4); // rf[4..5]
        float dvx = DT*((t3 + ra.w)*invm0);
        float dvy = DT*((t4 + rb.x)*invm0);
        float dvz = DT*((t5 + rb.y)*invm0 - 9.81f);
        float dwx = DT*(t0 + ra.x)*invm0;
        float dwy = DT*(t1 + ra.y)*invm0;
        float dwz = DT*(t2 + ra.z)*invm0;
        float4* o = (float4*)(rt + ((size_t)s*NENV + e)*8);
        o[0] = make_float4(dvx, dvy, dvz, 0.0f);
        o[1] = make_float4(dwx, dwy, dwz, 0.0f);
    }
}

// ===========================================================================
// KB: joint compose (proven round-6 k2)  [bid < 100]
//   + root chain over compact rt deltas  [bid >= 100]
// ===========================================================================
__global__ __launch_bounds__(256) void kb_kernel(
    const float* __restrict__ q_init,
    const float* __restrict__ qd_init,
    const float* __restrict__ target_ke,
    const float* __restrict__ target_kd,
    const float* __restrict__ body_mass,
    const float2* __restrict__ cws,
    const float*  __restrict__ rt,
    float* __restrict__ snap)
{
    const int bid = (int)blockIdx.x;
    if (bid < K2_BLOCKS) {
        const int r   = bid*256 + (int)threadIdx.x;
        const int env = r / NB;
        const int j   = r - env*NB;

        const float ke   = target_ke[env*NB + j];
        const float kd   = target_kd[env*NB + j];
        const float invm = 1.0f / (body_mass[env*(NB+1) + 1 + j] + 0.1f);
        const float a11  = 1.0f - DT*kd*invm;
        const float a10  = -DT*ke*invm;

        float m00 = 1.0f, m10 = 0.0f, m01 = 0.0f, m11 = 1.0f;
        #pragma unroll
        for (int k = 0; k < SPF; ++k) {
            m10 = a10*m00 + a11*m10;  m00 += DT*m10;
            m11 = a10*m01 + a11*m11;  m01 += DT*m11;
        }

        float jq  = q_init [env*32 + 7 + j];
        float jqd = qd_init[env*31 + 6 + j];
        snap[(size_t)env*SNAP_STRIDE + 13 + j] = jq;
        snap[(size_t)env*SNAP_STRIDE + 38 + j] = jqd;

        float2 c[NF01];
        #pragma unroll
        for (int f = 0; f < NF01; ++f) c[f] = cws[(size_t)f*NJ + r];
        #pragma unroll
        for (int f = 0; f < NF01; ++f) {
            float nq = m00*jq + m01*jqd + c[f].x;
            float nd = m10*jq + m11*jqd + c[f].y;
            jq = nq; jqd = nd;
            float* sp = snap + ((size_t)(f+1)*NENV + env) * SNAP_STRIDE;
            sp[13 + j] = jq;
            sp[38 + j] = jqd;
        }
    } else {
        const int env = (bid - K2_BLOCKS)*256 + (int)threadIdx.x;  // 0..1023

        float px = q_init[env*32+0], py = q_init[env*32+1], pz = q_init[env*32+2];
        float q0 = q_init[env*32+3], q1 = q_init[env*32+4];
        float q2 = q_init[env*32+5], q3 = q_init[env*32+6];
        float rn = 1.0f / fmaxf(sqrtf(q0*q0 + q1*q1 + q2*q2 + q3*q3), 1e-8f);
        float qx = q0*rn, qy = q1*rn, qz = q2*rn, qw = q3*rn;
        float wx = qd_init[env*31+0], wy = qd_init[env*31+1], wz = qd_init[env*31+2];
        float vx = qd_init[env*31+3], vy = qd_init[env*31+4], vz = qd_init[env*31+5];

        {
            float* sp = snap + (size_t)env * SNAP_STRIDE;
            sp[0]=px; sp[1]=py; sp[2]=pz;
            sp[3]=qx; sp[4]=qy; sp[5]=qz; sp[6]=qw;
            sp[7]=wx; sp[8]=wy; sp[9]=wz;
            sp[10]=vx; sp[11]=vy; sp[12]=vz;
        }

        #pragma unroll 1
        for (int f = 1; f < NFRM; ++f) {
            float4 d[2*SPF];
            #pragma unroll
            for (int k = 0; k < SPF; ++k) {
                const float4* p = (const float4*)(rt +
                    ((size_t)((f-1)*SPF + k)*NENV + env)*8);
                d[2*k]   = p[0];   // dv
                d[2*k+1] = p[1];   // dw
            }
            #pragma unroll
            for (int k = 0; k < SPF; ++k) {
                vx += d[2*k].x;  vy += d[2*k].y;  vz += d[2*k].z;
                wx += d[2*k+1].x; wy += d[2*k+1].y; wz += d[2*k+1].z;
                px += DT*vx; py += DT*vy; pz += DT*vz;
                float dqx =  wx*qw + wy*qz - wz*qy;
                float dqy = -wx*qz + wy*qw + wz*qx;
                float dqz =  wx*qy - wy*qx + wz*qw;
                float dqw = -(wx*qx + wy*qy + wz*qz);
                float nqx = qx + 0.5f*DT*dqx;
                float nqy = qy + 0.5f*DT*dqy;
                float nqz = qz + 0.5f*DT*dqz;
                float nqw = qw + 0.5f*DT*dqw;
                float nrm = sqrtf(nqx*nqx + nqy*nqy + nqz*nqz + nqw*nqw);
                float rq  = 1.0f / fmaxf(nrm, 1e-8f);
                qx = nqx*rq; qy = nqy*rq; qz = nqz*rq; qw = nqw*rq;
            }
            float* sp = snap + ((size_t)f*NENV + env) * SNAP_STRIDE;
            sp[0]=px; sp[1]=py; sp[2]=pz;
            sp[3]=qx; sp[4]=qy; sp[5]=qz; sp[6]=qw;
            sp[7]=wx; sp[8]=wy; sp[9]=wz;
            sp[10]=vx; sp[11]=vy; sp[12]=vz;
        }
    }
}

// ===========================================================================
// Legacy fallback: round-6 k1 (joint offsets + embedded sequential root).
// Used only when ws is too small for rt. Proven correct in round 6.
// ===========================================================================
__global__ __launch_bounds__(256) void k1_legacy(
    const float* __restrict__ q_init,
    const float* __restrict__ qd_init,
    const float* __restrict__ torques,
    const float* __restrict__ res_f,
    const float* __restrict__ refs,
    const float* __restrict__ target_ke,
    const float* __restrict__ target_kd,
    const float* __restrict__ body_mass,
    const float* __restrict__ joint_axes,
    float* __restrict__ snap,
    float2* __restrict__ cws)
{
    const int bid = (int)blockIdx.x;
    if (bid < K1_JBLOCKS) {
        const int g   = bid*256 + (int)threadIdx.x;
        const int f01 = g / NJ;
        const int r   = g - f01*NJ;
        const int env = r / NB;
        const int j   = r - env*NB;
        float a0 = joint_axes[j*3+0], a1 = joint_axes[j*3+1], a2 = joint_axes[j*3+2];
        float rn = 1.0f / fmaxf(sqrtf(a0*a0 + a1*a1 + a2*a2), 1e-8f);
        const float ax = a0*rn, ay = a1*rn, az = a2*rn;
        const float ke   = target_ke[env*NB + j];
        const float kd   = target_kd[env*NB + j];
        const float invm = 1.0f / (body_mass[env*(NB+1) + 1 + j] + 0.1f);
        const float dti  = DT*invm;
        const float a11  = 1.0f - DT*kd*invm;
        const float a10  = -DT*ke*invm;
        const int tq_off = env*31  + 6 + j;
        const int rf_off = env*156 + 6 + 6*j;
        float  ta[SPF], rr[SPF], r2[SPF];
        float2 ab[SPF];
        #pragma unroll
        for (int k = 0; k < SPF; ++k) {
            const int s = f01*SPF + k;
            ta[k] = torques[(size_t)s*TQ_SLAB + tq_off];
            rr[k] = refs   [(size_t)s*TQ_SLAB + tq_off];
            const float* rf = res_f + (size_t)s*RF_SLAB + rf_off;
            ab[k] = *(const float2*)rf;  r2[k] = rf[2];
        }
        float cq = 0.0f, cd = 0.0f;
        #pragma unroll
        for (int k = 0; k < SPF; ++k) {
            float u = ta[k] + ke*rr[k] + (ab[k].x*ax + ab[k].y*ay + r2[k]*az);
            cd = a10*cq + a11*cd + dti*u;
            cq += DT*cd;
        }
        cws[(size_t)f01*NJ + r] = make_float2(cq, cd);
    } else {
        const int env = (bid - K1_JBLOCKS)*256 + (int)threadIdx.x;
        float px = q_init[env*32+0], py = q_init[env*32+1], pz = q_init[env*32+2];
        float q0 = q_init[env*32+3], q1 = q_init[env*32+4];
        float q2 = q_init[env*32+5], q3 = q_init[env*32+6];
        float rn = 1.0f / fmaxf(sqrtf(q0*q0 + q1*q1 + q2*q2 + q3*q3), 1e-8f);
        float qx = q0*rn, qy = q1*rn, qz = q2*rn, qw = q3*rn;
        float wx = qd_init[env*31+0], wy = qd_init[env*31+1], wz = qd_init[env*31+2];
        float vx = qd_init[env*31+3], vy = qd_init[env*31+4], vz = qd_init[env*31+5];
        const float invm0 = 1.0f / (body_mass[env*(NB+1)] + 0.1f);
        {
            float* sp = snap + (size_t)env * SNAP_STRIDE;
            sp[0]=px; sp[1]=py; sp[2]=pz; sp[3]=qx; sp[4]=qy; sp[5]=qz; sp[6]=qw;
            sp[7]=wx; sp[8]=wy; sp[9]=wz; sp[10]=vx; sp[11]=vy; sp[12]=vz;
        }
        #pragma unroll 1
        for (int f = 1; f < NFRM; ++f) {
            float  tb[SPF][6]; float4 ra[SPF]; float2 rb[SPF];
            #pragma unroll
            for (int k = 0; k < SPF; ++k) {
                const int s = (f-1)*SPF + k;
                const float* tq = torques + (size_t)s*TQ_SLAB + env*31;
                tb[k][0]=tq[0]; tb[k][1]=tq[1]; tb[k][2]=tq[2];
                tb[k][3]=tq[3]; tb[k][4]=tq[4]; tb[k][5]=tq[5];
                const float* rf = res_f + (size_t)s*RF_SLAB + env*156;
                ra[k] = *(const float4*)rf; rb[k] = *(const float2*)(rf + 4);
            }
            #pragma unroll
            for (int k = 0; k < SPF; ++k) {
                vx += DT * ((tb[k][3] + ra[k].w) * invm0);
                vy += DT * ((tb[k][4] + rb[k].x) * invm0);
                vz += DT * ((tb[k][5] + rb[k].y) * invm0 - 9.81f);
                wx += DT * (tb[k][0] + ra[k].x) * invm0;
                wy += DT * (tb[k][1] + ra[k].y) * invm0;
                wz += DT * (tb[k][2] + ra[k].z) * invm0;
                px += DT * vx; py += DT * vy; pz += DT * vz;
                float dqx =  wx*qw + wy*qz - wz*qy;
                float dqy = -wx*qz + wy*qw + wz*qx;
                float dqz =  wx*qy - wy*qx + wz*qw;
                float dqw = -(wx*qx + wy*qy + wz*qz);
                float nqx = qx + 0.5f*DT*dqx, nqy = qy + 0.5f*DT*dqy;
                float nqz = qz + 0.5f*DT*dqz, nqw = qw + 0.5f*DT*dqw;
                float nrm = sqrtf(nqx*nqx + nqy*nqy + nqz*nqz + nqw*nqw);
                float rq  = 1.0f / fmaxf(nrm, 1e-8f);
                qx = nqx*rq; qy = nqy*rq; qz = nqz*rq; qw = nqw*rq;
            }
            float* sp = snap + ((size_t)f*NENV + env) * SNAP_STRIDE;
            sp[0]=px; sp[1]=py; sp[2]=pz; sp[3]=qx; sp[4]=qy; sp[5]=qz; sp[6]=qw;
            sp[7]=wx; sp[8]=wy; sp[9]=wz; sp[10]=vx; sp[11]=vy; sp[12]=vz;
        }
    }
}

// ===========================================================================
// KC: FK. 64 chains/block; snap staged transposed in LDS ([64][65], no bank
// conflicts), axes/offsets prenormalized in LDS; small rolling link loop
// (no local arrays -> no scratch); two passes reuse one out-staging buffer.
// ===========================================================================
__global__ __launch_bounds__(64) void fk_kernel(
    const float* __restrict__ snap,
    const float* __restrict__ joint_axes,
    const float* __restrict__ joint_offsets,
    float* __restrict__ out)
{
    __shared__ float s_snap[64*65];    // 16640 B
    __shared__ float s_axn[NB*3];      // normalized axes
    __shared__ float s_off[NB*3];
    __shared__ float s_out[64*182];    // 46592 B (reused by both passes)

    const int tid   = (int)threadIdx.x;
    const int tbase = (int)blockIdx.x*64;
    const int f     = tbase >> 10;
    const int e0    = tbase & (NENV-1);

    if (tid < NB) {
        float a0 = joint_axes[tid*3+0];
        float a1 = joint_axes[tid*3+1];
        float a2 = joint_axes[tid*3+2];
        float rn = 1.0f / fmaxf(sqrtf(a0*a0 + a1*a1 + a2*a2), 1e-8f);
        s_axn[tid*3+0] = a0*rn; s_axn[tid*3+1] = a1*rn; s_axn[tid*3+2] = a2*rn;
        s_off[tid*3+0] = joint_offsets[tid*3+0];
        s_off[tid*3+1] = joint_offsets[tid*3+1];
        s_off[tid*3+2] = joint_offsets[tid*3+2];
    }
    #pragma unroll 4
    for (int i = 0; i < 64; ++i)
        s_snap[i*65 + tid] = snap[(size_t)(tbase + i)*SNAP_STRIDE + tid];
    __syncthreads();

    const float* ss = s_snap + tid*65;

    // ---------------- pass 0: positions (p, q only) ----------------
    {
        float px=ss[0], py=ss[1], pz=ss[2];
        float qx=ss[3], qy=ss[4], qz=ss[5], qw=ss[6];
        float* po = s_out + tid*182;
        po[0]=px; po[1]=py; po[2]=pz; po[3]=qx; po[4]=qy; po[5]=qz; po[6]=qw;
        #pragma unroll 1
        for (int b = 0; b < NB; ++b) {
            float axn=s_axn[b*3+0], ayn=s_axn[b*3+1], azn=s_axn[b*3+2];
            float ox=s_off[b*3+0], oy=s_off[b*3+1], oz=s_off[b*3+2];
            float tx = 2.0f*(qy*oz - qz*oy);
            float ty = 2.0f*(qz*ox - qx*oz);
            float tz = 2.0f*(qx*oy - qy*ox);
            px += ox + qw*tx + (qy*tz - qz*ty);
            py += oy + qw*ty + (qz*tx - qx*tz);
            pz += oz + qw*tz + (qx*ty - qy*tx);
            float sh, ch;
            __sincosf(0.5f*ss[13+b], &sh, &ch);
            float bx = axn*sh, by = ayn*sh, bz = azn*sh, bw = ch;
            float qcx = qw*bx + qx*bw + qy*bz - qz*by;
            float qcy = qw*by - qx*bz + qy*bw + qz*bx;
            float qcz = qw*bz + qx*by - qy*bx + qz*bw;
            float qcw = qw*bw - qx*bx - qy*by - qz*bz;
            qx=qcx; qy=qcy; qz=qcz; qw=qcw;
            float* p = po + (b+1)*7;
            p[0]=px; p[1]=py; p[2]=pz; p[3]=qx; p[4]=qy; p[5]=qz; p[6]=qw;
        }
    }
    __syncthreads();
    {
        float4* o4 = (float4*)(out + (size_t)(f*NENV + e0)*182);
        const float4* l4 = (const float4*)s_out;
        for (int k = tid; k < 64*182/4; k += 64) o4[k] = l4[k];
    }
    __syncthreads();

    // ---------------- pass 1: velocities (full chain) ----------------
    {
        float px=ss[0], py=ss[1], pz=ss[2];
        float qx=ss[3], qy=ss[4], qz=ss[5], qw=ss[6];
        float wx=ss[7], wy=ss[8], wz=ss[9];
        float vx=ss[10], vy=ss[11], vz=ss[12];
        float* vo = s_out + tid*156;
        vo[0]=wx; vo[1]=wy; vo[2]=wz; vo[3]=vx; vo[4]=vy; vo[5]=vz;
        #pragma unroll 1
        for (int b = 0; b < NB; ++b) {
            float axn=s_axn[b*3+0], ayn=s_axn[b*3+1], azn=s_axn[b*3+2];
            float ox=s_off[b*3+0], oy=s_off[b*3+1], oz=s_off[b*3+2];
            float tx = 2.0f*(qy*oz - qz*oy);
            float ty = 2.0f*(qz*ox - qx*oz);
            float tz = 2.0f*(qx*oy - qy*ox);
            float owx = ox + qw*tx + (qy*tz - qz*ty);
            float owy = oy + qw*ty + (qz*tx - qx*tz);
            float owz = oz + qw*tz + (qx*ty - qy*tx);
            px += owx; py += owy; pz += owz;
            float sh, ch;
            __sincosf(0.5f*ss[13+b], &sh, &ch);
            float bx = axn*sh, by = ayn*sh, bz = azn*sh, bw = ch;
            float qcx = qw*bx + qx*bw + qy*bz - qz*by;
            float qcy = qw*by - qx*bz + qy*bw + qz*bx;
            float qcz = qw*bz + qx*by - qy*bx + qz*bw;
            float qcw = qw*bw - qx*bx - qy*by - qz*bz;
            float ux = 2.0f*(qy*azn - qz*ayn);
            float uy = 2.0f*(qz*axn - qx*azn);
            float uz = 2.0f*(qx*ayn - qy*axn);
            float awx = axn + qw*ux + (qy*uz - qz*uy);
            float awy = ayn + qw*uy + (qz*ux - qx*uz);
            float awz = azn + qw*uz + (qx*uy - qy*ux);
            float thd = ss[38+b];
            float nwx = wx + awx*thd, nwy = wy + awy*thd, nwz = wz + awz*thd;
            vx += (wy*owz - wz*owy);
            vy += (wz*owx - wx*owz);
            vz += (wx*owy - wy*owx);
            wx=nwx; wy=nwy; wz=nwz;
            qx=qcx; qy=qcy; qz=qcz; qw=qcw;
            float* p = vo + (b+1)*6;
            p[0]=wx; p[1]=wy; p[2]=wz; p[3]=vx; p[4]=vy; p[5]=vz;
        }
    }
    __syncthreads();
    {
        float4* o4 = (float4*)(out + (size_t)NFRM*NENV*182 + (size_t)(f*NENV + e0)*156);
        const float4* l4 = (const float4*)s_out;
        for (int k = tid; k < 64*156/4; k += 64) o4[k] = l4[k];
    }
}

extern "C" void kernel_launch(void* const* d_in, const int* in_sizes, int n_in,
                              void* d_out, int out_size, void* d_ws, size_t ws_size,
                              hipStream_t stream)
{
    const float* q_init     = (const float*)d_in[0];
    const float* qd_init    = (const float*)d_in[1];
    const float* torques    = (const float*)d_in[2];
    const float* res_f      = (const float*)d_in[3];
    const float* refs       = (const float*)d_in[4];
    const float* target_ke  = (const float*)d_in[5];
    const float* target_kd  = (const float*)d_in[6];
    const float* body_mass  = (const float*)d_in[7];
    const float* joint_axes = (const float*)d_in[8];
    const float* joint_offs = (const float*)d_in[9];
    float*  out  = (float*)d_out;
    float*  snap = (float*)d_ws;
    float2* cws  = (float2*)((float*)d_ws + SNAP_FLOATS);
    float*  rt   = (float*)d_ws + SNAP_FLOATS + CWS_FLOATS;

    if (ws_size >= WS_NEED_NEW) {
        ka_kernel<<<dim3(K1_JBLOCKS + KA_RDBLOCKS), dim3(256), 0, stream>>>(
            torques, res_f, refs, target_ke, target_kd, body_mass,
            joint_axes, cws, rt);
        kb_kernel<<<dim3(K2_BLOCKS + RC_BLOCKS), dim3(256), 0, stream>>>(
            q_init, qd_init, target_ke, target_kd, body_mass, cws, rt, snap);
    } else {
        k1_legacy<<<dim3(K1_JBLOCKS + NENV/256), dim3(256), 0, stream>>>(
            q_init, qd_init, torques, res_f, refs,
            target_ke, target_kd, body_mass, joint_axes, snap, cws);
        kb_kernel<<<dim3(K2_BLOCKS), dim3(256), 0, stream>>>(
            q_init, qd_init, target_ke, target_kd, body_mass, cws, rt, snap);
    }

    fk_kernel<<<dim3(NFRM*NENV/64), dim3(64), 0, stream>>>(
        snap, joint_axes, joint_offs, out);
}

// Round 8
// 250.577 us; speedup vs baseline: 1.4681x; 1.0057x over previous
//
#include <hip/hip_runtime.h>

#define DT     0.0005f
#define NENV   1024
#define NB     25
#define SPF    10
#define NSTEP  150
#define NFRM   16
#define NF01   15
#define TQ_SLAB (NENV*31)
#define RF_SLAB (NENV*156)
#define SNAP_STRIDE 64
#define SNAP_FLOATS (NFRM*NENV*SNAP_STRIDE)      // 1,048,576
#define NJ      (NENV*NB)                        // 25600
#define CWS_FLOATS (NJ*NF01*2)                   // 768,000
#define RT_FLOATS  (NSTEP*NENV*8)                // 1,228,800
#define K1_JBLOCKS (NJ*NF01/256)                 // 1500
#define KA_RDBLOCKS (NSTEP*NENV/256)             // 600
#define K2_BLOCKS  (NJ/256)                      // 100
#define RC_BLOCKS  (NENV/256)                    // 4
#define WS_NEED_NEW    ((size_t)(SNAP_FLOATS + CWS_FLOATS + RT_FLOATS)*4)
#define WS_NEED_LEGACY ((size_t)(SNAP_FLOATS + CWS_FLOATS)*4)

// ===========================================================================
// KA: joint per-frame affine offsets  [bid < 1500]
//   + root per-(step,env) deltas into transposed rt buffer  [bid >= 1500]
// __launch_bounds__(256,4): VGPR cap 128 so the 60-float frame batch stays
// live and all 40 loads issue back-to-back (round-7 had VGPR=32 -> serialized).
// ===========================================================================
__global__ __launch_bounds__(256, 4) void ka_kernel(
    const float* __restrict__ torques,
    const float* __restrict__ res_f,
    const float* __restrict__ refs,
    const float* __restrict__ target_ke,
    const float* __restrict__ target_kd,
    const float* __restrict__ body_mass,
    const float* __restrict__ joint_axes,
    float2* __restrict__ cws,          // (15, 25600)
    float*  __restrict__ rt)           // (150, 1024, 8)
{
    const int bid = (int)blockIdx.x;
    if (bid < K1_JBLOCKS) {
        const int g   = bid*256 + (int)threadIdx.x;
        const int f01 = g / NJ;
        const int r   = g - f01*NJ;
        const int env = r / NB;
        const int j   = r - env*NB;

        float a0 = joint_axes[j*3+0];
        float a1 = joint_axes[j*3+1];
        float a2 = joint_axes[j*3+2];
        float rn = 1.0f / fmaxf(sqrtf(a0*a0 + a1*a1 + a2*a2), 1e-8f);
        const float ax = a0*rn, ay = a1*rn, az = a2*rn;
        const float ke   = target_ke[env*NB + j];
        const float kd   = target_kd[env*NB + j];
        const float invm = 1.0f / (body_mass[env*(NB+1) + 1 + j] + 0.1f);
        const float dti  = DT*invm;
        const float a11  = 1.0f - DT*kd*invm;
        const float a10  = -DT*ke*invm;

        const int tq_off = env*31  + 6 + j;
        const int rf_off = env*156 + 6 + 6*j;

        float  ta[SPF], rr[SPF], r2[SPF];
        float2 ab[SPF];
        #pragma unroll
        for (int k = 0; k < SPF; ++k) {
            const int s = f01*SPF + k;
            ta[k] = torques[(size_t)s*TQ_SLAB + tq_off];
            rr[k] = refs   [(size_t)s*TQ_SLAB + tq_off];
            const float* rf = res_f + (size_t)s*RF_SLAB + rf_off;
            ab[k] = *(const float2*)rf;
            r2[k] = rf[2];
        }
        float cq = 0.0f, cd = 0.0f;
        #pragma unroll
        for (int k = 0; k < SPF; ++k) {
            float u = ta[k] + ke*rr[k] + (ab[k].x*ax + ab[k].y*ay + r2[k]*az);
            cd = a10*cq + a11*cd + dti*u;
            cq += DT*cd;
        }
        cws[(size_t)f01*NJ + r] = make_float2(cq, cd);
    } else {
        // root deltas: thread per (step, env)
        const int g = (bid - K1_JBLOCKS)*256 + (int)threadIdx.x;  // 0..153599
        const int s = g >> 10;
        const int e = g & (NENV-1);
        const float invm0 = 1.0f / (body_mass[e*(NB+1)] + 0.1f);
        const float* tq = torques + (size_t)s*TQ_SLAB + e*31;
        const float t0=tq[0], t1=tq[1], t2=tq[2], t3=tq[3], t4=tq[4], t5=tq[5];
        const float* rf = res_f + (size_t)s*RF_SLAB + e*156;
        const float4 ra = *(const float4*)rf;       // rf[0..3]
        const float2 rb = *(const float2*)(rf + 4); // rf[4..5]
        float dvx = DT*((t3 + ra.w)*invm0);
        float dvy = DT*((t4 + rb.x)*invm0);
        float dvz = DT*((t5 + rb.y)*invm0 - 9.81f);
        float dwx = DT*(t0 + ra.x)*invm0;
        float dwy = DT*(t1 + ra.y)*invm0;
        float dwz = DT*(t2 + ra.z)*invm0;
        float4* o = (float4*)(rt + ((size_t)s*NENV + e)*8);
        o[0] = make_float4(dvx, dvy, dvz, 0.0f);
        o[1] = make_float4(dwx, dwy, dwz, 0.0f);
    }
}

// ===========================================================================
// KB: joint compose  [bid < 100]  +  root chain over rt deltas  [bid >= 100]
// ===========================================================================
__global__ __launch_bounds__(256, 4) void kb_kernel(
    const float* __restrict__ q_init,
    const float* __restrict__ qd_init,
    const float* __restrict__ target_ke,
    const float* __restrict__ target_kd,
    const float* __restrict__ body_mass,
    const float2* __restrict__ cws,
    const float*  __restrict__ rt,
    float* __restrict__ snap)
{
    const int bid = (int)blockIdx.x;
    if (bid < K2_BLOCKS) {
        const int r   = bid*256 + (int)threadIdx.x;
        const int env = r / NB;
        const int j   = r - env*NB;

        const float ke   = target_ke[env*NB + j];
        const float kd   = target_kd[env*NB + j];
        const float invm = 1.0f / (body_mass[env*(NB+1) + 1 + j] + 0.1f);
        const float a11  = 1.0f - DT*kd*invm;
        const float a10  = -DT*ke*invm;

        float m00 = 1.0f, m10 = 0.0f, m01 = 0.0f, m11 = 1.0f;
        #pragma unroll
        for (int k = 0; k < SPF; ++k) {
            m10 = a10*m00 + a11*m10;  m00 += DT*m10;
            m11 = a10*m01 + a11*m11;  m01 += DT*m11;
        }

        float jq  = q_init [env*32 + 7 + j];
        float jqd = qd_init[env*31 + 6 + j];
        snap[(size_t)env*SNAP_STRIDE + 13 + j] = jq;
        snap[(size_t)env*SNAP_STRIDE + 38 + j] = jqd;

        float2 c[NF01];
        #pragma unroll
        for (int f = 0; f < NF01; ++f) c[f] = cws[(size_t)f*NJ + r];
        #pragma unroll
        for (int f = 0; f < NF01; ++f) {
            float nq = m00*jq + m01*jqd + c[f].x;
            float nd = m10*jq + m11*jqd + c[f].y;
            jq = nq; jqd = nd;
            float* sp = snap + ((size_t)(f+1)*NENV + env) * SNAP_STRIDE;
            sp[13 + j] = jq;
            sp[38 + j] = jqd;
        }
    } else {
        const int env = (bid - K2_BLOCKS)*256 + (int)threadIdx.x;  // 0..1023

        float px = q_init[env*32+0], py = q_init[env*32+1], pz = q_init[env*32+2];
        float q0 = q_init[env*32+3], q1 = q_init[env*32+4];
        float q2 = q_init[env*32+5], q3 = q_init[env*32+6];
        float rn = 1.0f / fmaxf(sqrtf(q0*q0 + q1*q1 + q2*q2 + q3*q3), 1e-8f);
        float qx = q0*rn, qy = q1*rn, qz = q2*rn, qw = q3*rn;
        float wx = qd_init[env*31+0], wy = qd_init[env*31+1], wz = qd_init[env*31+2];
        float vx = qd_init[env*31+3], vy = qd_init[env*31+4], vz = qd_init[env*31+5];

        {
            float* sp = snap + (size_t)env * SNAP_STRIDE;
            sp[0]=px; sp[1]=py; sp[2]=pz;
            sp[3]=qx; sp[4]=qy; sp[5]=qz; sp[6]=qw;
            sp[7]=wx; sp[8]=wy; sp[9]=wz;
            sp[10]=vx; sp[11]=vy; sp[12]=vz;
        }

        #pragma unroll 1
        for (int f = 1; f < NFRM; ++f) {
            float4 d[2*SPF];
            #pragma unroll
            for (int k = 0; k < SPF; ++k) {
                const float4* p = (const float4*)(rt +
                    ((size_t)((f-1)*SPF + k)*NENV + env)*8);
                d[2*k]   = p[0];   // dv
                d[2*k+1] = p[1];   // dw
            }
            #pragma unroll
            for (int k = 0; k < SPF; ++k) {
                vx += d[2*k].x;  vy += d[2*k].y;  vz += d[2*k].z;
                wx += d[2*k+1].x; wy += d[2*k+1].y; wz += d[2*k+1].z;
                px += DT*vx; py += DT*vy; pz += DT*vz;
                float dqx =  wx*qw + wy*qz - wz*qy;
                float dqy = -wx*qz + wy*qw + wz*qx;
                float dqz =  wx*qy - wy*qx + wz*qw;
                float dqw = -(wx*qx + wy*qy + wz*qz);
                float nqx = qx + 0.5f*DT*dqx;
                float nqy = qy + 0.5f*DT*dqy;
                float nqz = qz + 0.5f*DT*dqz;
                float nqw = qw + 0.5f*DT*dqw;
                float nrm = sqrtf(nqx*nqx + nqy*nqy + nqz*nqz + nqw*nqw);
                float rq  = 1.0f / fmaxf(nrm, 1e-8f);
                qx = nqx*rq; qy = nqy*rq; qz = nqz*rq; qw = nqw*rq;
            }
            float* sp = snap + ((size_t)f*NENV + env) * SNAP_STRIDE;
            sp[0]=px; sp[1]=py; sp[2]=pz;
            sp[3]=qx; sp[4]=qy; sp[5]=qz; sp[6]=qw;
            sp[7]=wx; sp[8]=wy; sp[9]=wz;
            sp[10]=vx; sp[11]=vy; sp[12]=vz;
        }
    }
}

// ===========================================================================
// Legacy fallback (round-6 k1) if ws too small for rt.
// ===========================================================================
__global__ __launch_bounds__(256, 4) void k1_legacy(
    const float* __restrict__ q_init,
    const float* __restrict__ qd_init,
    const float* __restrict__ torques,
    const float* __restrict__ res_f,
    const float* __restrict__ refs,
    const float* __restrict__ target_ke,
    const float* __restrict__ target_kd,
    const float* __restrict__ body_mass,
    const float* __restrict__ joint_axes,
    float* __restrict__ snap,
    float2* __restrict__ cws)
{
    const int bid = (int)blockIdx.x;
    if (bid < K1_JBLOCKS) {
        const int g   = bid*256 + (int)threadIdx.x;
        const int f01 = g / NJ;
        const int r   = g - f01*NJ;
        const int env = r / NB;
        const int j   = r - env*NB;
        float a0 = joint_axes[j*3+0], a1 = joint_axes[j*3+1], a2 = joint_axes[j*3+2];
        float rn = 1.0f / fmaxf(sqrtf(a0*a0 + a1*a1 + a2*a2), 1e-8f);
        const float ax = a0*rn, ay = a1*rn, az = a2*rn;
        const float ke   = target_ke[env*NB + j];
        const float kd   = target_kd[env*NB + j];
        const float invm = 1.0f / (body_mass[env*(NB+1) + 1 + j] + 0.1f);
        const float dti  = DT*invm;
        const float a11  = 1.0f - DT*kd*invm;
        const float a10  = -DT*ke*invm;
        const int tq_off = env*31  + 6 + j;
        const int rf_off = env*156 + 6 + 6*j;
        float  ta[SPF], rr[SPF], r2[SPF];
        float2 ab[SPF];
        #pragma unroll
        for (int k = 0; k < SPF; ++k) {
            const int s = f01*SPF + k;
            ta[k] = torques[(size_t)s*TQ_SLAB + tq_off];
            rr[k] = refs   [(size_t)s*TQ_SLAB + tq_off];
            const float* rf = res_f + (size_t)s*RF_SLAB + rf_off;
            ab[k] = *(const float2*)rf;  r2[k] = rf[2];
        }
        float cq = 0.0f, cd = 0.0f;
        #pragma unroll
        for (int k = 0; k < SPF; ++k) {
            float u = ta[k] + ke*rr[k] + (ab[k].x*ax + ab[k].y*ay + r2[k]*az);
            cd = a10*cq + a11*cd + dti*u;
            cq += DT*cd;
        }
        cws[(size_t)f01*NJ + r] = make_float2(cq, cd);
    } else {
        const int env = (bid - K1_JBLOCKS)*256 + (int)threadIdx.x;
        float px = q_init[env*32+0], py = q_init[env*32+1], pz = q_init[env*32+2];
        float q0 = q_init[env*32+3], q1 = q_init[env*32+4];
        float q2 = q_init[env*32+5], q3 = q_init[env*32+6];
        float rn = 1.0f / fmaxf(sqrtf(q0*q0 + q1*q1 + q2*q2 + q3*q3), 1e-8f);
        float qx = q0*rn, qy = q1*rn, qz = q2*rn, qw = q3*rn;
        float wx = qd_init[env*31+0], wy = qd_init[env*31+1], wz = qd_init[env*31+2];
        float vx = qd_init[env*31+3], vy = qd_init[env*31+4], vz = qd_init[env*31+5];
        const float invm0 = 1.0f / (body_mass[env*(NB+1)] + 0.1f);
        {
            float* sp = snap + (size_t)env * SNAP_STRIDE;
            sp[0]=px; sp[1]=py; sp[2]=pz; sp[3]=qx; sp[4]=qy; sp[5]=qz; sp[6]=qw;
            sp[7]=wx; sp[8]=wy; sp[9]=wz; sp[10]=vx; sp[11]=vy; sp[12]=vz;
        }
        #pragma unroll 1
        for (int f = 1; f < NFRM; ++f) {
            float  tb[SPF][6]; float4 ra[SPF]; float2 rb[SPF];
            #pragma unroll
            for (int k = 0; k < SPF; ++k) {
                const int s = (f-1)*SPF + k;
                const float* tq = torques + (size_t)s*TQ_SLAB + env*31;
                tb[k][0]=tq[0]; tb[k][1]=tq[1]; tb[k][2]=tq[2];
                tb[k][3]=tq[3]; tb[k][4]=tq[4]; tb[k][5]=tq[5];
                const float* rf = res_f + (size_t)s*RF_SLAB + env*156;
                ra[k] = *(const float4*)rf; rb[k] = *(const float2*)(rf + 4);
            }
            #pragma unroll
            for (int k = 0; k < SPF; ++k) {
                vx += DT * ((tb[k][3] + ra[k].w) * invm0);
                vy += DT * ((tb[k][4] + rb[k].x) * invm0);
                vz += DT * ((tb[k][5] + rb[k].y) * invm0 - 9.81f);
                wx += DT * (tb[k][0] + ra[k].x) * invm0;
                wy += DT * (tb[k][1] + ra[k].y) * invm0;
                wz += DT * (tb[k][2] + ra[k].z) * invm0;
                px += DT * vx; py += DT * vy; pz += DT * vz;
                float dqx =  wx*qw + wy*qz - wz*qy;
                float dqy = -wx*qz + wy*qw + wz*qx;
                float dqz =  wx*qy - wy*qx + wz*qw;
                float dqw = -(wx*qx + wy*qy + wz*qz);
                float nqx = qx + 0.5f*DT*dqx, nqy = qy + 0.5f*DT*dqy;
                float nqz = qz + 0.5f*DT*dqz, nqw = qw + 0.5f*DT*dqw;
                float nrm = sqrtf(nqx*nqx + nqy*nqy + nqz*nqz + nqw*nqw);
                float rq  = 1.0f / fmaxf(nrm, 1e-8f);
                qx = nqx*rq; qy = nqy*rq; qz = nqz*rq; qw = nqw*rq;
            }
            float* sp = snap + ((size_t)f*NENV + env) * SNAP_STRIDE;
            sp[0]=px; sp[1]=py; sp[2]=pz; sp[3]=qx; sp[4]=qy; sp[5]=qz; sp[6]=qw;
            sp[7]=wx; sp[8]=wy; sp[9]=wz; sp[10]=vx; sp[11]=vy; sp[12]=vz;
        }
    }
}

// ===========================================================================
// KC: FK. 64 chains/block; snap transposed in LDS ([64][65]); axes/offsets
// prenormalized; rolling link loop; coalesced float4 flush.
// ===========================================================================
__global__ __launch_bounds__(64) void fk_kernel(
    const float* __restrict__ snap,
    const float* __restrict__ joint_axes,
    const float* __restrict__ joint_offsets,
    float* __restrict__ out)
{
    __shared__ float s_snap[64*65];    // 16640 B
    __shared__ float s_axn[NB*3];
    __shared__ float s_off[NB*3];
    __shared__ float s_out[64*182];    // 46592 B

    const int tid   = (int)threadIdx.x;
    const int tbase = (int)blockIdx.x*64;
    const int f     = tbase >> 10;
    const int e0    = tbase & (NENV-1);

    if (tid < NB) {
        float a0 = joint_axes[tid*3+0];
        float a1 = joint_axes[tid*3+1];
        float a2 = joint_axes[tid*3+2];
        float rn = 1.0f / fmaxf(sqrtf(a0*a0 + a1*a1 + a2*a2), 1e-8f);
        s_axn[tid*3+0] = a0*rn; s_axn[tid*3+1] = a1*rn; s_axn[tid*3+2] = a2*rn;
        s_off[tid*3+0] = joint_offsets[tid*3+0];
        s_off[tid*3+1] = joint_offsets[tid*3+1];
        s_off[tid*3+2] = joint_offsets[tid*3+2];
    }
    #pragma unroll 4
    for (int i = 0; i < 64; ++i)
        s_snap[i*65 + tid] = snap[(size_t)(tbase + i)*SNAP_STRIDE + tid];
    __syncthreads();

    const float* ss = s_snap + tid*65;

    // pass 0: positions
    {
        float px=ss[0], py=ss[1], pz=ss[2];
        float qx=ss[3], qy=ss[4], qz=ss[5], qw=ss[6];
        float* po = s_out + tid*182;
        po[0]=px; po[1]=py; po[2]=pz; po[3]=qx; po[4]=qy; po[5]=qz; po[6]=qw;
        #pragma unroll 1
        for (int b = 0; b < NB; ++b) {
            float axn=s_axn[b*3+0], ayn=s_axn[b*3+1], azn=s_axn[b*3+2];
            float ox=s_off[b*3+0], oy=s_off[b*3+1], oz=s_off[b*3+2];
            float tx = 2.0f*(qy*oz - qz*oy);
            float ty = 2.0f*(qz*ox - qx*oz);
            float tz = 2.0f*(qx*oy - qy*ox);
            px += ox + qw*tx + (qy*tz - qz*ty);
            py += oy + qw*ty + (qz*tx - qx*tz);
            pz += oz + qw*tz + (qx*ty - qy*tx);
            float sh, ch;
            __sincosf(0.5f*ss[13+b], &sh, &ch);
            float bx = axn*sh, by = ayn*sh, bz = azn*sh, bw = ch;
            float qcx = qw*bx + qx*bw + qy*bz - qz*by;
            float qcy = qw*by - qx*bz + qy*bw + qz*bx;
            float qcz = qw*bz + qx*by - qy*bx + qz*bw;
            float qcw = qw*bw - qx*bx - qy*by - qz*bz;
            qx=qcx; qy=qcy; qz=qcz; qw=qcw;
            float* p = po + (b+1)*7;
            p[0]=px; p[1]=py; p[2]=pz; p[3]=qx; p[4]=qy; p[5]=qz; p[6]=qw;
        }
    }
    __syncthreads();
    {
        float4* o4 = (float4*)(out + (size_t)(f*NENV + e0)*182);
        const float4* l4 = (const float4*)s_out;
        for (int k = tid; k < 64*182/4; k += 64) o4[k] = l4[k];
    }
    __syncthreads();

    // pass 1: velocities
    {
        float px=ss[0], py=ss[1], pz=ss[2];
        float qx=ss[3], qy=ss[4], qz=ss[5], qw=ss[6];
        float wx=ss[7], wy=ss[8], wz=ss[9];
        float vx=ss[10], vy=ss[11], vz=ss[12];
        float* vo = s_out + tid*156;
        vo[0]=wx; vo[1]=wy; vo[2]=wz; vo[3]=vx; vo[4]=vy; vo[5]=vz;
        #pragma unroll 1
        for (int b = 0; b < NB; ++b) {
            float axn=s_axn[b*3+0], ayn=s_axn[b*3+1], azn=s_axn[b*3+2];
            float ox=s_off[b*3+0], oy=s_off[b*3+1], oz=s_off[b*3+2];
            float tx = 2.0f*(qy*oz - qz*oy);
            float ty = 2.0f*(qz*ox - qx*oz);
            float tz = 2.0f*(qx*oy - qy*ox);
            float owx = ox + qw*tx + (qy*tz - qz*ty);
            float owy = oy + qw*ty + (qz*tx - qx*tz);
            float owz = oz + qw*tz + (qx*ty - qy*tx);
            px += owx; py += owy; pz += owz;
            float sh, ch;
            __sincosf(0.5f*ss[13+b], &sh, &ch);
            float bx = axn*sh, by = ayn*sh, bz = azn*sh, bw = ch;
            float qcx = qw*bx + qx*bw + qy*bz - qz*by;
            float qcy = qw*by - qx*bz + qy*bw + qz*bx;
            float qcz = qw*bz + qx*by - qy*bx + qz*bw;
            float qcw = qw*bw - qx*bx - qy*by - qz*bz;
            float ux = 2.0f*(qy*azn - qz*ayn);
            float uy = 2.0f*(qz*axn - qx*azn);
            float uz = 2.0f*(qx*ayn - qy*axn);
            float awx = axn + qw*ux + (qy*uz - qz*uy);
            float awy = ayn + qw*uy + (qz*ux - qx*uz);
            float awz = azn + qw*uz + (qx*uy - qy*ux);
            float thd = ss[38+b];
            float nwx = wx + awx*thd, nwy = wy + awy*thd, nwz = wz + awz*thd;
            vx += (wy*owz - wz*owy);
            vy += (wz*owx - wx*owz);
            vz += (wx*owy - wy*owx);
            wx=nwx; wy=nwy; wz=nwz;
            qx=qcx; qy=qcy; qz=qcz; qw=qcw;
            float* p = vo + (b+1)*6;
            p[0]=wx; p[1]=wy; p[2]=wz; p[3]=vx; p[4]=vy; p[5]=vz;
        }
    }
    __syncthreads();
    {
        float4* o4 = (float4*)(out + (size_t)NFRM*NENV*182 + (size_t)(f*NENV + e0)*156);
        const float4* l4 = (const float4*)s_out;
        for (int k = tid; k < 64*156/4; k += 64) o4[k] = l4[k];
    }
}

extern "C" void kernel_launch(void* const* d_in, const int* in_sizes, int n_in,
                              void* d_out, int out_size, void* d_ws, size_t ws_size,
                              hipStream_t stream)
{
    const float* q_init     = (const float*)d_in[0];
    const float* qd_init    = (const float*)d_in[1];
    const float* torques    = (const float*)d_in[2];
    const float* res_f      = (const float*)d_in[3];
    const float* refs       = (const float*)d_in[4];
    const float* target_ke  = (const float*)d_in[5];
    const float* target_kd  = (const float*)d_in[6];
    const float* body_mass  = (const float*)d_in[7];
    const float* joint_axes = (const float*)d_in[8];
    const float* joint_offs = (const float*)d_in[9];
    float*  out  = (float*)d_out;
    float*  snap = (float*)d_ws;
    float2* cws  = (float2*)((float*)d_ws + SNAP_FLOATS);
    float*  rt   = (float*)d_ws + SNAP_FLOATS + CWS_FLOATS;

    if (ws_size >= WS_NEED_NEW) {
        ka_kernel<<<dim3(K1_JBLOCKS + KA_RDBLOCKS), dim3(256), 0, stream>>>(
            torques, res_f, refs, target_ke, target_kd, body_mass,
            joint_axes, cws, rt);
        kb_kernel<<<dim3(K2_BLOCKS + RC_BLOCKS), dim3(256), 0, stream>>>(
            q_init, qd_init, target_ke, target_kd, body_mass, cws, rt, snap);
    } else {
        k1_legacy<<<dim3(K1_JBLOCKS + NENV/256), dim3(256), 0, stream>>>(
            q_init, qd_init, torques, res_f, refs,
            target_ke, target_kd, body_mass, joint_axes, snap, cws);
        kb_kernel<<<dim3(K2_BLOCKS), dim3(256), 0, stream>>>(
            q_init, qd_init, target_ke, target_kd, body_mass, cws, rt, snap);
    }

    fk_kernel<<<dim3(NFRM*NENV/64), dim3(64), 0, stream>>>(
        snap, joint_axes, joint_offs, out);
}